// Round 6
// baseline (278.634 us; speedup 1.0000x reference)
//
#include <hip/hip_runtime.h>

// ZeroUpsampling: out[b,c,2h,2w] = x[b,c,h,w], zeros elsewhere.
// x: (4,32,540,960) f32 -> out: (4,32,1080,1920) f32
//
// R5: OUTPUT-LINEAR mapping. Thread t writes output float4 quad t0 + i*STRIDE
// -> the grid's store stream is one dense linear front over the whole 1.06 GB
// output (exactly like the 6.5-6.9 TB/s fillBuffer), instead of the previous
// even-rows-only / odd-rows-only combs at 7.68 KB half-density.
//
// Grid stride = 518,400 quads = exactly 1080 output rows, so each thread's
// output-row parity is invariant across iterations:
//   even-row threads: load in2[(r0/2)*480 + q0], store {v.x,0,v.y,0}
//   odd-row threads:  store zeros
// Waves straddling a row boundary (~1 in 7.5) execute both masked paths;
// boundaries are 7.68 KB aligned so no partial cachelines and no extra bytes.

typedef float vfloat2 __attribute__((ext_vector_type(2)));
typedef float vfloat4 __attribute__((ext_vector_type(4)));

constexpr int W_IN  = 960;
constexpr int H_IN  = 540;
constexpr int BC    = 4 * 32;
constexpr int P2PR  = W_IN / 2;            // 480 float2 per input row
constexpr int OQPR  = (2 * W_IN) / 4;      // 480 float4 per output row
constexpr int OROWS = BC * 2 * H_IN;       // 138,240 output rows
constexpr long OQ_TOTAL = (long)OROWS * OQPR;  // 66,355,200 output quads

constexpr int BLOCK  = 256;
constexpr int GRID   = 2025;               // 2025*256 = 518,400 = 480*1080
constexpr int STRIDE = GRID * BLOCK;       // quads per iteration (1080 rows)
constexpr int ITERS  = (int)(OQ_TOTAL / STRIDE);   // 128, exact
constexpr int IN_STEP = (STRIDE / OQPR / 2) * P2PR; // 540 in-rows * 480 = 259,200

static_assert(STRIDE % OQPR == 0, "stride must be whole output rows");
static_assert((STRIDE / OQPR) % 2 == 0, "row advance must be even (parity invariant)");
static_assert(OQ_TOTAL % STRIDE == 0, "iteration count must be exact");

__global__ __launch_bounds__(BLOCK)
void zero_upsample_kernel(const vfloat2* __restrict__ in2, vfloat4* __restrict__ out) {
    const int t0 = blockIdx.x * BLOCK + threadIdx.x;
    const int r0 = t0 / OQPR;              // output row of this thread's first quad
    const int q0 = t0 - r0 * OQPR;         // quad within row

    vfloat4* op = out + t0;                // dense linear write front

    if ((r0 & 1) == 0) {
        // data-carrying even output rows
        const vfloat2* ip = in2 + (size_t)(r0 >> 1) * P2PR + q0;
        #pragma unroll 8
        for (int i = 0; i < ITERS; ++i) {
            vfloat2 v = __builtin_nontemporal_load(ip);
            vfloat4 e = {v.x, 0.f, v.y, 0.f};
            __builtin_nontemporal_store(e, op);
            ip += IN_STEP;
            op += STRIDE;
        }
    } else {
        // zero odd output rows
        const vfloat4 z = {0.f, 0.f, 0.f, 0.f};
        #pragma unroll 8
        for (int i = 0; i < ITERS; ++i) {
            __builtin_nontemporal_store(z, op);
            op += STRIDE;
        }
    }
}

extern "C" void kernel_launch(void* const* d_in, const int* in_sizes, int n_in,
                              void* d_out, int out_size, void* d_ws, size_t ws_size,
                              hipStream_t stream) {
    const vfloat2* in2 = (const vfloat2*)d_in[0];
    vfloat4*       out = (vfloat4*)d_out;
    zero_upsample_kernel<<<GRID, BLOCK, 0, stream>>>(in2, out);
}

// Round 7
// 251.818 us; speedup vs baseline: 1.1065x; 1.1065x over previous
//
#include <hip/hip_runtime.h>

// ZeroUpsampling: out[b,c,2h,2w] = x[b,c,h,w], zeros elsewhere.
// x: (4,32,540,960) f32 -> out: (4,32,1080,1920) f32
//
// R6: 16B reads + wave-private LDS bounce -> all streams dwordx4-dense.
// Problem: 16B input (4 px) -> 32B output; same-lane expansion forces either
// 8B loads (R1-R5, read-limited ~2.5 TB/s effective) or comb stores (R0).
// Fix: each wave loads 64 float4 (1KB dense), stages to LDS, and each lane
// reads back float2 #lane and #(64+lane) of the wave's 128-float2 window.
// Those map to output quads o(k)=960*(k/480)+k%480 and o(k+64) -> the wave's
// two data stores are dense 64-quad runs; zero stores at +480 quads (odd row)
// are equally dense. Every output quad written exactly once.
//
// Grid stride per iter = 8100 waves * 128 float2 = 1,036,800 = 2160 input
// rows exactly -> all row/quad decompositions advance by compile-time
// constants; 32 iterations exactly, no epilogue.

typedef float vfloat2 __attribute__((ext_vector_type(2)));
typedef float vfloat4 __attribute__((ext_vector_type(4)));

constexpr int W_IN  = 960;
constexpr int H_IN  = 540;
constexpr int BC    = 4 * 32;
constexpr int P2PR  = W_IN / 2;                    // 480 float2 per input row
constexpr int OQPR  = (2 * W_IN) / 4;              // 480 float4 per output row
constexpr long TOT_F2 = (long)BC * H_IN * P2PR;    // 33,177,600 input float2
constexpr long TOT_F4 = TOT_F2 / 2;                // 16,588,800 input float4

constexpr int BLOCK = 256;
constexpr int GRID  = 2025;
constexpr int WAVES = GRID * (BLOCK / 64);         // 8100
constexpr int F4_STRIDE = WAVES * 64;              // 518,400 float4 per iter
constexpr int S2 = F4_STRIDE * 2;                  // 1,036,800 float2 per iter
constexpr int ITERS = (int)(TOT_F4 / F4_STRIDE);   // 32, exact
constexpr int R_STEP = S2 / P2PR;                  // 2160 input rows per iter
constexpr int O_STEP = R_STEP * 2 * OQPR;          // 2,073,600 output quads per iter

static_assert(S2 % P2PR == 0, "grid stride must be whole input rows");
static_assert((long)F4_STRIDE * ITERS == TOT_F4, "exact coverage");

__global__ __launch_bounds__(BLOCK)
void zero_upsample_kernel(const vfloat4* __restrict__ in4, vfloat4* __restrict__ out) {
    __shared__ vfloat4 lds4[BLOCK];                // 4KB: 1KB per wave
    const int tid   = blockIdx.x * BLOCK + threadIdx.x;
    const int wid   = tid >> 6;                    // global wave id
    const int lane  = tid & 63;
    float* wbuf = (float*)(lds4 + (threadIdx.x & ~63));  // this wave's 256-float slot

    const vfloat4* ip = in4 + tid;                 // dense 16B/lane load stream

    // The wave's 128-float2 window starts at 128*wid; lane handles float2
    // k1 = 128*wid + lane and k2 = k1 + 64. Output quad o = 960*(k/480)+k%480.
    const int k1 = 128 * wid + lane;
    const int k2 = k1 + 64;
    const int r1 = k1 / P2PR, q1 = k1 - P2PR * r1;
    const int r2 = k2 / P2PR, q2 = k2 - P2PR * r2;

    vfloat4* o1 = out + (size_t)(2 * r1) * OQPR + q1;   // even-row data quad
    vfloat4* o2 = out + (size_t)(2 * r2) * OQPR + q2;
    vfloat4* z1 = o1 + OQPR;                            // odd-row zero quad
    vfloat4* z2 = o2 + OQPR;

    const vfloat4 zero = {0.f, 0.f, 0.f, 0.f};

    #pragma unroll 2
    for (int i = 0; i < ITERS; ++i) {
        vfloat4 v = __builtin_nontemporal_load(ip);
        *(vfloat4*)(wbuf + 4 * lane) = v;               // ds_write_b128 (wave-private, no barrier)
        vfloat2 s1 = *(const vfloat2*)(wbuf + 2 * lane);        // float2 #lane
        vfloat2 s2 = *(const vfloat2*)(wbuf + 128 + 2 * lane);  // float2 #(64+lane)
        vfloat4 e1 = {s1.x, 0.f, s1.y, 0.f};
        vfloat4 e2 = {s2.x, 0.f, s2.y, 0.f};
        __builtin_nontemporal_store(e1, o1);
        __builtin_nontemporal_store(zero, z1);
        __builtin_nontemporal_store(e2, o2);
        __builtin_nontemporal_store(zero, z2);
        ip += F4_STRIDE;
        o1 += O_STEP;  z1 += O_STEP;
        o2 += O_STEP;  z2 += O_STEP;
    }
}

extern "C" void kernel_launch(void* const* d_in, const int* in_sizes, int n_in,
                              void* d_out, int out_size, void* d_ws, size_t ws_size,
                              hipStream_t stream) {
    const vfloat4* in4 = (const vfloat4*)d_in[0];
    vfloat4*       out = (vfloat4*)d_out;
    zero_upsample_kernel<<<GRID, BLOCK, 0, stream>>>(in4, out);
}